// Round 2
// baseline (3087.742 us; speedup 1.0000x reference)
//
#include <hip/hip_runtime.h>
#include <hip/hip_bf16.h>

// Problem constants (from setup_inputs): B=4, W=16, N=2048, E=4096,
// Dn=128, De=64, Dl=64, ds=16, d_conv=4, expand=2.
// node:  d=128, di=256, dtr=8, Bt=8192,  T=131072
// trace: d=64,  di=128, dtr=4, Bt=16384, T=262144
// log:   d=64,  di=128, dtr=4, Bt=8192,  T=131072

#define DEV_INLINE __device__ __forceinline__

DEV_INLINE float silu_f(float v) { return v / (1.0f + __expf(-v)); }

// ---------------------------------------------------------------------------
// Fully fused per-sequence Mamba kernel:
//   in_proj GEMM + causal conv + SiLU + x_proj + (dt_proj + softplus +
//   selective scan with dt on the fly) + D-skip + z-gating + out_proj GEMM.
// One workgroup = one sequence (L=16). NT == DI threads (thread == channel
// for the conv/scan phases). TRN=true writes the final transposed output
// layout directly (used for the trace branch).
// ---------------------------------------------------------------------------
template<int D, int DI, int DTR, int NT, int DO, bool TRN>
__global__ __launch_bounds__(NT) void mamba_fused(
    const float* __restrict__ x,        // (B, 16, Nr, D)
    const float* __restrict__ in_w,     // (2*DI, D)
    const float* __restrict__ conv_w,   // (DI, 4)
    const float* __restrict__ conv_b,   // (DI)
    const float* __restrict__ xproj_w,  // (DTR+32, DI)
    const float* __restrict__ dt_w,     // (DI, DTR)
    const float* __restrict__ dt_b,     // (DI)
    const float* __restrict__ A_log,    // (DI, 16)
    const float* __restrict__ Dp,       // (DI)
    const float* __restrict__ out_w,    // (DO, DI)
    float* __restrict__ y_out,          // !TRN: (Bt*16, DO) ; TRN: (B,16,Nr,DO)
    int Nr)
{
    static_assert(NT == DI, "thread==channel mapping requires NT==DI");
    constexpr int NJ = DTR + 32;

    __shared__ float sx[16][D];        // x tile
    __shared__ float sxc[16][DI];      // xin -> u=silu(conv) -> g (scan output)
    __shared__ float sz[16][DI];       // z half of in_proj
    __shared__ float sw[8][2 * DI][2]; // staged weight K-tile, c-pair layout
    __shared__ float sdbc[16][NJ];     // x_proj output (dt_in | B | C)

    const int tid = threadIdx.x;
    const int seq = blockIdx.x;
    const int b = seq / Nr, n = seq % Nr;
    const float* xb = x + ((size_t)b * 16 * Nr + n) * D;

    // ---- load x (16 x D) ----
    for (int i4 = tid; i4 < 4 * D; i4 += NT) {
        int w = i4 / (D / 4), c4 = i4 % (D / 4);
        float4 v = *(const float4*)(xb + (size_t)w * Nr * D + c4 * 4);
        *(float4*)&sx[w][c4 * 4] = v;
    }
    __syncthreads();

    // ---- in_proj GEMM: (16 x D) @ (D x 2DI) -> xin | z ----
    constexpr int TJ = NT / 2;
    const int tw = tid / TJ;   // 0..1 (8 rows each) — wave-uniform
    const int tj = tid % TJ;
    {
        float acc[8][4] = {};
        for (int kt = 0; kt < D / 16; ++kt) {
            // stage in_w[:, kt*16 .. +16) as c-pairs: sw[kp][j][parity]
            for (int i4 = tid; i4 < 2 * DI * 4; i4 += NT) {
                int j = i4 >> 2, kq = (i4 & 3) * 4;
                float4 v = *(const float4*)(in_w + (size_t)j * D + kt * 16 + kq);
                int kp = kq >> 1;
                *(float2*)&sw[kp][j][0]     = make_float2(v.x, v.y);
                *(float2*)&sw[kp + 1][j][0] = make_float2(v.z, v.w);
            }
            __syncthreads();
#pragma unroll
            for (int kp = 0; kp < 8; ++kp) {
                float2 a[8], bb[4];
#pragma unroll
                for (int i = 0; i < 8; ++i)
                    a[i] = *(const float2*)&sx[tw * 8 + i][kt * 16 + kp * 2];
#pragma unroll
                for (int jj = 0; jj < 4; ++jj)
                    bb[jj] = *(const float2*)&sw[kp][tj + TJ * jj][0];
#pragma unroll
                for (int i = 0; i < 8; ++i)
#pragma unroll
                    for (int jj = 0; jj < 4; ++jj)
                        acc[i][jj] += a[i].x * bb[jj].x + a[i].y * bb[jj].y;
            }
            __syncthreads();
        }
#pragma unroll
        for (int i = 0; i < 8; ++i) {
            int w = tw * 8 + i;
#pragma unroll
            for (int jj = 0; jj < 4; ++jj) {
                int j = tj + TJ * jj;
                if (j < DI) sxc[w][j] = acc[i][jj];
                else        sz[w][j - DI] = acc[i][jj];
            }
        }
    }
    __syncthreads();

    // ---- causal conv (k=4) + SiLU, per-channel, in place ----
    const int ch = tid;
    float4 cw = *(const float4*)(conv_w + ch * 4);
    float cb = conv_b[ch];
    float xin_t[16];
#pragma unroll
    for (int t = 0; t < 16; ++t) xin_t[t] = sxc[t][ch];
    float u[16];
#pragma unroll
    for (int t = 0; t < 16; ++t) {
        float a = cb + cw.w * xin_t[t];
        if (t >= 1) a += cw.z * xin_t[t - 1];
        if (t >= 2) a += cw.y * xin_t[t - 2];
        if (t >= 3) a += cw.x * xin_t[t - 3];
        u[t] = silu_f(a);
        sxc[t][ch] = u[t];
    }
    __syncthreads();

    // ---- x_proj: (16 x DI) @ (DI x NJ) -> sdbc ----
    for (int p = tid; p < 16 * NJ; p += NT) {
        int w = p / NJ, j = p % NJ;
        const float* wr = xproj_w + (size_t)j * DI;
        float s = 0.f;
        for (int c4 = 0; c4 < DI / 4; ++c4) {
            float4 av = *(const float4*)&sxc[w][c4 * 4];
            float4 wv = *(const float4*)(wr + c4 * 4);
            s += av.x * wv.x + av.y * wv.y + av.z * wv.z + av.w * wv.w;
        }
        sdbc[w][j] = s;
    }
    __syncthreads();

    // ---- selective scan (thread == channel), dt computed on the fly ----
    // Overwrites sxc[t][ch] with g = y * silu(z) (own column only).
    {
        float dtw[DTR];
#pragma unroll
        for (int r = 0; r < DTR; ++r) dtw[r] = dt_w[ch * DTR + r];
        float dtb = dt_b[ch];
        float Dch = Dp[ch];
        float a_s[16];
#pragma unroll
        for (int s = 0; s < 16; ++s) a_s[s] = -__expf(A_log[ch * 16 + s]);
        float h[16];
#pragma unroll
        for (int s = 0; s < 16; ++s) h[s] = 0.f;

        for (int t = 0; t < 16; ++t) {
            float dtv = dtb;
#pragma unroll
            for (int r = 0; r < DTR; ++r) dtv += sdbc[t][r] * dtw[r];
            dtv = (dtv > 20.f) ? dtv : __logf(1.f + __expf(dtv));  // softplus
            float du = dtv * u[t];
            float yt = 0.f;
#pragma unroll
            for (int s = 0; s < 16; ++s) {
                float dA = __expf(dtv * a_s[s]);
                h[s] = dA * h[s] + du * sdbc[t][DTR + s];
                yt += h[s] * sdbc[t][DTR + 16 + s];
            }
            yt += u[t] * Dch;
            float zv = sz[t][ch];
            sxc[t][ch] = yt * silu_f(zv);
        }
    }
    // (barrier before out_proj compute is provided by the stage-sync below)

    // ---- out_proj GEMM: y(16 x DO) = g(16 x DI) @ out_w(DO x DI)^T ----
    constexpr int TO = NT / 4;
    const int tw2 = tid / TO;      // 0..3 (4 rows each); node: wave-uniform
    const int to  = tid % TO;
    float acc2[4][2] = {};
    for (int kt = 0; kt < DI / 16; ++kt) {
        for (int i4 = tid; i4 < DO * 4; i4 += NT) {
            int j = i4 >> 2, kq = (i4 & 3) * 4;
            float4 v = *(const float4*)(out_w + (size_t)j * DI + kt * 16 + kq);
            int kp = kq >> 1;
            *(float2*)&sw[kp][j][0]     = make_float2(v.x, v.y);
            *(float2*)&sw[kp + 1][j][0] = make_float2(v.z, v.w);
        }
        __syncthreads();   // also orders scan's sxc writes before reads below
#pragma unroll
        for (int kp = 0; kp < 8; ++kp) {
            float2 a[4], bb[2];
#pragma unroll
            for (int i = 0; i < 4; ++i)
                a[i] = *(const float2*)&sxc[tw2 * 4 + i][kt * 16 + kp * 2];
#pragma unroll
            for (int jj = 0; jj < 2; ++jj)
                bb[jj] = *(const float2*)&sw[kp][to + TO * jj][0];
#pragma unroll
            for (int i = 0; i < 4; ++i)
#pragma unroll
                for (int jj = 0; jj < 2; ++jj)
                    acc2[i][jj] += a[i].x * bb[jj].x + a[i].y * bb[jj].y;
        }
        __syncthreads();
    }
#pragma unroll
    for (int i = 0; i < 4; ++i) {
        int w = tw2 * 4 + i;
#pragma unroll
        for (int jj = 0; jj < 2; ++jj) {
            int o = to + TO * jj;
            if (!TRN)
                y_out[((size_t)seq * 16 + w) * DO + o] = acc2[i][jj];
            else
                y_out[(((size_t)(b * 16 + w)) * Nr + n) * DO + o] = acc2[i][jj];
        }
    }
}

// ---------------------------------------------------------------------------
// Mix: cat = [yn | yl] (131072 x 192); mixed = silu(cat @ W^T + b) + cat;
// split + transposed write to out_node / out_log.
// tile 128 x 64, 256 threads, 8x4 per thread. N=2048 hardcoded.
// ---------------------------------------------------------------------------
__global__ __launch_bounds__(256) void mix_kernel(
    const float* __restrict__ yn, const float* __restrict__ yl,
    const float* __restrict__ mixW, const float* __restrict__ mixb,
    float* __restrict__ out_node, float* __restrict__ out_log)
{
    __shared__ float sa[128][17];
    __shared__ float sb[64][17];
    const int tid = threadIdx.x;
    const int m0 = blockIdx.x * 128;
    const int c0 = blockIdx.y * 64;
    const int tr = tid & 15, tc = tid >> 4;
    float acc[8][4] = {};
    for (int kt = 0; kt < 12; ++kt) {
        int k0 = kt * 16;
        for (int i4 = tid; i4 < 512; i4 += 256) {
            int r = i4 >> 2, kq = (i4 & 3) * 4;
            int t = m0 + r, k = k0 + kq;
            float4 v;
            if (k < 128) v = *(const float4*)(yn + (size_t)t * 128 + k);
            else         v = *(const float4*)(yl + (size_t)t * 64 + (k - 128));
            sa[r][kq] = v.x; sa[r][kq + 1] = v.y; sa[r][kq + 2] = v.z; sa[r][kq + 3] = v.w;
        }
        {
            int c = tid >> 2, kq = (tid & 3) * 4;
            float4 v = *(const float4*)(mixW + (size_t)(c0 + c) * 192 + k0 + kq);
            sb[c][kq] = v.x; sb[c][kq + 1] = v.y; sb[c][kq + 2] = v.z; sb[c][kq + 3] = v.w;
        }
        __syncthreads();
#pragma unroll
        for (int kk = 0; kk < 16; ++kk) {
            float a[8], bv[4];
#pragma unroll
            for (int i = 0; i < 8; ++i) a[i] = sa[tr + 16 * i][kk];
#pragma unroll
            for (int j = 0; j < 4; ++j) bv[j] = sb[tc + 16 * j][kk];
#pragma unroll
            for (int i = 0; i < 8; ++i)
#pragma unroll
                for (int j = 0; j < 4; ++j) acc[i][j] += a[i] * bv[j];
        }
        __syncthreads();
    }
#pragma unroll
    for (int i = 0; i < 8; ++i) {
        int t = m0 + tr + 16 * i;
        int w = t & 15, s = t >> 4;
        int b = s >> 11, n = s & 2047;
#pragma unroll
        for (int j = 0; j < 4; ++j) {
            int cg = c0 + tc + 16 * j;
            float catv = (cg < 128) ? yn[(size_t)t * 128 + cg]
                                    : yl[(size_t)t * 64 + cg - 128];
            float v = acc[i][j] + mixb[cg];
            float m = silu_f(v) + catv;
            if (cg < 128)
                out_node[((size_t)(b * 16 + w) * 2048 + n) * 128 + cg] = m;
            else
                out_log[((size_t)(b * 16 + w) * 2048 + n) * 64 + (cg - 128)] = m;
        }
    }
}

// ---------------------------------------------------------------------------
extern "C" void kernel_launch(void* const* d_in, const int* in_sizes, int n_in,
                              void* d_out, int out_size, void* d_ws, size_t ws_size,
                              hipStream_t stream) {
    const float* x_node = (const float*)d_in[0];
    const float* x_trace = (const float*)d_in[1];
    const float* x_log = (const float*)d_in[2];
    // node params: 3..11  trace: 12..20  log: 21..29  mix: 30,31
    const float* n_in_w  = (const float*)d_in[3];
    const float* n_cw    = (const float*)d_in[4];
    const float* n_cb    = (const float*)d_in[5];
    const float* n_xp    = (const float*)d_in[6];
    const float* n_dtw   = (const float*)d_in[7];
    const float* n_dtb   = (const float*)d_in[8];
    const float* n_Al    = (const float*)d_in[9];
    const float* n_D     = (const float*)d_in[10];
    const float* n_ow    = (const float*)d_in[11];
    const float* t_in_w  = (const float*)d_in[12];
    const float* t_cw    = (const float*)d_in[13];
    const float* t_cb    = (const float*)d_in[14];
    const float* t_xp    = (const float*)d_in[15];
    const float* t_dtw   = (const float*)d_in[16];
    const float* t_dtb   = (const float*)d_in[17];
    const float* t_Al    = (const float*)d_in[18];
    const float* t_D     = (const float*)d_in[19];
    const float* t_ow    = (const float*)d_in[20];
    const float* l_in_w  = (const float*)d_in[21];
    const float* l_cw    = (const float*)d_in[22];
    const float* l_cb    = (const float*)d_in[23];
    const float* l_xp    = (const float*)d_in[24];
    const float* l_dtw   = (const float*)d_in[25];
    const float* l_dtb   = (const float*)d_in[26];
    const float* l_Al    = (const float*)d_in[27];
    const float* l_D     = (const float*)d_in[28];
    const float* l_ow    = (const float*)d_in[29];
    const float* mix_W   = (const float*)d_in[30];
    const float* mix_b   = (const float*)d_in[31];
    (void)in_sizes; (void)n_in; (void)out_size; (void)ws_size;

    float* out = (float*)d_out;
    float* out_trace = out + 16777216;   // B*W*N*Dn
    float* out_log   = out + 33554432;   // + B*W*E*De

    float* ws = (float*)d_ws;
    float* yn = ws;                // 131072*128 = 16,777,216 floats (64 MB)
    float* yl = ws + 16777216;     // 131072*64  =  8,388,608 floats (32 MB)
    // total ws use: 100,663,296 bytes

    // node -> yn (token-major)
    mamba_fused<128, 256, 8, 256, 128, false><<<8192, 256, 0, stream>>>(
        x_node, n_in_w, n_cw, n_cb, n_xp, n_dtw, n_dtb, n_Al, n_D, n_ow, yn, 2048);
    // trace -> final transposed output directly
    mamba_fused<64, 128, 4, 128, 64, true><<<16384, 128, 0, stream>>>(
        x_trace, t_in_w, t_cw, t_cb, t_xp, t_dtw, t_dtb, t_Al, t_D, t_ow, out_trace, 4096);
    // log -> yl (token-major)
    mamba_fused<64, 128, 4, 128, 64, false><<<8192, 128, 0, stream>>>(
        x_log, l_in_w, l_cw, l_cb, l_xp, l_dtw, l_dtb, l_Al, l_D, l_ow, yl, 2048);
    // mix + transposed final writes for node/log
    mix_kernel<<<dim3(1024, 3), 256, 0, stream>>>(yn, yl, mix_W, mix_b, out, out_log);
}

// Round 4
// 2551.747 us; speedup vs baseline: 1.2101x; 1.2101x over previous
//
#include <hip/hip_runtime.h>

// B=4, W=16, N=2048, E=4096, Dn=128, De=64, Dl=64, ds=16, d_conv=4, expand=2
// node:  d=128, di=256, dtr=8, T=131072, nr_l2=11
// trace: d=64,  di=128, dtr=4, T=262144, nr_l2=12
// log:   d=64,  di=128, dtr=4, T=131072, nr_l2=11

#define DEV_INLINE __device__ __forceinline__

typedef __attribute__((ext_vector_type(8))) short bf16x8;
typedef __attribute__((ext_vector_type(4))) float f32x4;

DEV_INLINE float silu_f(float v) { return v / (1.0f + __expf(-v)); }

DEV_INLINE unsigned short f2bf(float f) {            // fp32 -> bf16 (RNE)
    unsigned int u = __float_as_uint(f);
    u += 0x7fffu + ((u >> 16) & 1u);
    return (unsigned short)(u >> 16);
}
DEV_INLINE float bf2f(unsigned short b) {
    return __uint_as_float(((unsigned int)b) << 16);
}

// ---------------------------------------------------------------------------
// One-time weight split: w (fp32, n elems) -> bf16 hi + lo arrays.
// ---------------------------------------------------------------------------
__global__ __launch_bounds__(256) void wsplit(
    const float* __restrict__ src, unsigned short* __restrict__ dh,
    unsigned short* __restrict__ dl, int n)
{
    int i = blockIdx.x * 256 + threadIdx.x;
    if (i >= n) return;
    float v = src[i];
    unsigned short h = f2bf(v);
    dh[i] = h;
    dl[i] = f2bf(v - bf2f(h));
}

// ---------------------------------------------------------------------------
// Split-bf16 MFMA GEMM:  C[M][N] = A[M][K](fp32) @ W[N][K]^T, W pre-split
// into bf16 hi/lo. A split on the fly. acc += Ah*Wh + Ah*Wl + Al*Wh.
// BM=128, BK=32, 256 threads (4 waves).
// GATHER: A rows gathered from x (B,16,Nr,D) token order.
// TRN:    C scattered to (B,16,Nr,N) final layout.
// ---------------------------------------------------------------------------
template<int BN, bool GATHER, bool TRN>
__global__ __launch_bounds__(256) void gemm_split(
    const float* __restrict__ A,
    const unsigned short* __restrict__ Wh,
    const unsigned short* __restrict__ Wl,
    float* __restrict__ C, int M, int N, int K,
    long m_off, int nr_l2)
{
    constexpr int BM = 128, BK = 32;
    __shared__ unsigned short sAh[BM][40], sAl[BM][40];   // 80 B pitch
    __shared__ unsigned short sBh[BN][40], sBl[BN][40];

    const int tid = threadIdx.x;
    const int m0 = blockIdx.x * BM;
    const int n0 = blockIdx.y * BN;
    const int lane = tid & 63, wv = tid >> 6;
    const int lr = lane & 15, lg = lane >> 4;
    constexpr int MT = (BN == 128) ? 4 : 2;
    const int wm = (BN == 128) ? (wv >> 1) * 64 : wv * 32;
    const int wn = (BN == 128) ? (wv & 1) * 64 : 0;

    f32x4 acc[MT][4] = {};

    for (int kt = 0; kt < K / BK; ++kt) {
        const int k0 = kt * BK;
        // ---- stage A tile (fp32 -> bf16 hi/lo on the fly) ----
#pragma unroll
        for (int p = 0; p < BM * BK / 1024; ++p) {
            int i4 = tid + p * 256;
            int r = i4 >> 3, c4 = (i4 & 7) * 4;
            const float* src;
            if (GATHER) {
                long rg = m_off + m0 + r;
                long sq = rg >> 4; int w = (int)(rg & 15);
                long b = sq >> nr_l2, n = sq & ((1L << nr_l2) - 1);
                src = A + ((((b << 4) + w) << nr_l2) + n) * (long)K + k0 + c4;
            } else {
                src = A + (size_t)(m0 + r) * K + k0 + c4;
            }
            float4 v = *(const float4*)src;
            ushort4 hi, lo;
            hi.x = f2bf(v.x); lo.x = f2bf(v.x - bf2f(hi.x));
            hi.y = f2bf(v.y); lo.y = f2bf(v.y - bf2f(hi.y));
            hi.z = f2bf(v.z); lo.z = f2bf(v.z - bf2f(hi.z));
            hi.w = f2bf(v.w); lo.w = f2bf(v.w - bf2f(hi.w));
            *(ushort4*)&sAh[r][c4] = hi;
            *(ushort4*)&sAl[r][c4] = lo;
        }
        // ---- stage pre-split W tile (pure copies) ----
#pragma unroll
        for (int p = 0; p < BN * BK / 2048; ++p) {
            int i8 = tid + p * 256;
            int r = i8 >> 2, c8 = (i8 & 3) * 8;
            *(bf16x8*)&sBh[r][c8] = *(const bf16x8*)(Wh + (size_t)(n0 + r) * K + k0 + c8);
            *(bf16x8*)&sBl[r][c8] = *(const bf16x8*)(Wl + (size_t)(n0 + r) * K + k0 + c8);
        }
        __syncthreads();

        bf16x8 aH[MT], aL[MT];
#pragma unroll
        for (int mt = 0; mt < MT; ++mt) {
            aH[mt] = *(const bf16x8*)&sAh[wm + mt * 16 + lr][lg * 8];
            aL[mt] = *(const bf16x8*)&sAl[wm + mt * 16 + lr][lg * 8];
        }
#pragma unroll
        for (int nt = 0; nt < 4; ++nt) {
            bf16x8 bH = *(const bf16x8*)&sBh[wn + nt * 16 + lr][lg * 8];
            bf16x8 bL = *(const bf16x8*)&sBl[wn + nt * 16 + lr][lg * 8];
#pragma unroll
            for (int mt = 0; mt < MT; ++mt) {
                acc[mt][nt] = __builtin_amdgcn_mfma_f32_16x16x32_bf16(aH[mt], bH, acc[mt][nt], 0, 0, 0);
                acc[mt][nt] = __builtin_amdgcn_mfma_f32_16x16x32_bf16(aH[mt], bL, acc[mt][nt], 0, 0, 0);
                acc[mt][nt] = __builtin_amdgcn_mfma_f32_16x16x32_bf16(aL[mt], bH, acc[mt][nt], 0, 0, 0);
            }
        }
        __syncthreads();
    }

    // ---- epilogue: D layout col=lane&15, row=(lane>>4)*4+reg (m89) ----
#pragma unroll
    for (int mt = 0; mt < MT; ++mt) {
        int row0 = m0 + wm + mt * 16 + lg * 4;
#pragma unroll
        for (int nt = 0; nt < 4; ++nt) {
            int col = n0 + wn + nt * 16 + lr;
#pragma unroll
            for (int q = 0; q < 4; ++q) {
                int row = row0 + q;
                if (!TRN) {
                    C[(size_t)row * N + col] = acc[mt][nt][q];
                } else {
                    long rg = m_off + row;
                    long sq = rg >> 4; int w = (int)(rg & 15);
                    long b = sq >> nr_l2, e = sq & ((1L << nr_l2) - 1);
                    C[((((b << 4) + w) << nr_l2) + e) * (long)N + col] = acc[mt][nt][q];
                }
            }
        }
    }
}

// ---------------------------------------------------------------------------
// Middle kernel: conv(k=4)+SiLU + x_proj + dt_proj/softplus + selective scan
// + D-skip + z-gate. One block = one sequence (16 tokens), thread == channel.
// Fast path: A_log rows are log(1..16) -> dA = r^(s+1), r = exp(-dt)
// (runtime-checked, general fallback kept).
// ---------------------------------------------------------------------------
template<int DI, int DTR>
__global__ __launch_bounds__(DI) void mamba_mid(
    const float* __restrict__ xz,       // (Tc, 2*DI)
    const float* __restrict__ conv_w,   // (DI, 4)
    const float* __restrict__ conv_b,   // (DI)
    const float* __restrict__ xproj_w,  // (DTR+32, DI)
    const float* __restrict__ dt_w,     // (DI, DTR)
    const float* __restrict__ dt_b,     // (DI)
    const float* __restrict__ A_log,    // (DI, 16)
    const float* __restrict__ Dp,       // (DI)
    float* __restrict__ g)              // (Tc, DI)
{
    constexpr int NJ = DTR + 32;
    __shared__ float su[16][DI];
    __shared__ float sdbc[16][NJ];

    const int ch = threadIdx.x;
    const long s = blockIdx.x;
    const float* xzs = xz + (size_t)s * 16 * (2 * DI);

    float xin[16], z[16];
#pragma unroll
    for (int t = 0; t < 16; ++t) {
        xin[t] = xzs[t * 2 * DI + ch];
        z[t]   = xzs[t * 2 * DI + DI + ch];
    }

    float4 cw = *(const float4*)(conv_w + ch * 4);
    float cb = conv_b[ch];
    float u[16];
#pragma unroll
    for (int t = 0; t < 16; ++t) {
        float a = cb + cw.w * xin[t];
        if (t >= 1) a += cw.z * xin[t - 1];
        if (t >= 2) a += cw.y * xin[t - 2];
        if (t >= 3) a += cw.x * xin[t - 3];
        u[t] = silu_f(a);
        su[t][ch] = u[t];
    }
    __syncthreads();

    // x_proj: (16 x DI) @ (DI x NJ)
    for (int p = ch; p < 16 * NJ; p += DI) {
        int w = p / NJ, j = p % NJ;
        const float* wr = xproj_w + (size_t)j * DI;
        float acc = 0.f;
        for (int c4 = 0; c4 < DI / 4; ++c4) {
            float4 av = *(const float4*)&su[w][c4 * 4];
            float4 wv = *(const float4*)(wr + c4 * 4);
            acc += av.x * wv.x + av.y * wv.y + av.z * wv.z + av.w * wv.w;
        }
        sdbc[w][j] = acc;
    }
    __syncthreads();

    float dtw[DTR];
#pragma unroll
    for (int r = 0; r < DTR; ++r) dtw[r] = dt_w[ch * DTR + r];
    float dtb = dt_b[ch];
    float Dch = Dp[ch];
    float a_s[16];
    bool geo = true;
#pragma unroll
    for (int ss = 0; ss < 16; ++ss) {
        a_s[ss] = -__expf(A_log[ch * 16 + ss]);
        geo = geo && (__builtin_fabsf(a_s[ss] + (float)(ss + 1)) < 1e-3f);
    }
    float h[16];
#pragma unroll
    for (int ss = 0; ss < 16; ++ss) h[ss] = 0.f;

    float* gout = g + (size_t)s * 16 * DI + ch;
    for (int t = 0; t < 16; ++t) {
        float dtv = dtb;
#pragma unroll
        for (int r = 0; r < DTR; ++r) dtv += sdbc[t][r] * dtw[r];
        dtv = (dtv > 20.f) ? dtv : __logf(1.f + __expf(dtv));   // softplus
        float du = dtv * u[t];
        float yt = 0.f;
        if (geo) {
            float r1 = __expf(-dtv);
            float pw = 1.f;
#pragma unroll
            for (int ss = 0; ss < 16; ++ss) {
                pw *= r1;                         // pw = r1^(ss+1) = exp(dt*a_s)
                h[ss] = pw * h[ss] + du * sdbc[t][DTR + ss];
                yt += h[ss] * sdbc[t][DTR + 16 + ss];
            }
        } else {
#pragma unroll
            for (int ss = 0; ss < 16; ++ss) {
                float dA = __expf(dtv * a_s[ss]);
                h[ss] = dA * h[ss] + du * sdbc[t][DTR + ss];
                yt += h[ss] * sdbc[t][DTR + 16 + ss];
            }
        }
        yt += u[t] * Dch;
        gout[(size_t)t * DI] = yt * silu_f(z[t]);
    }
}

// ---------------------------------------------------------------------------
// Mix (chunk-aware): cat = [yn_c | yl_c] (Tc x 192);
// mixed = silu(cat @ W^T + b) + cat; transposed split-write to out.
// ---------------------------------------------------------------------------
__global__ __launch_bounds__(256) void mix_kernel(
    const float* __restrict__ yn, const float* __restrict__ yl,
    const float* __restrict__ mixW, const float* __restrict__ mixb,
    float* __restrict__ out_node, float* __restrict__ out_log, long m_off)
{
    __shared__ float sa[128][17];
    __shared__ float sb[64][17];
    const int tid = threadIdx.x;
    const int m0 = blockIdx.x * 128;
    const int c0 = blockIdx.y * 64;
    const int tr = tid & 15, tc = tid >> 4;
    float acc[8][4] = {};
    for (int kt = 0; kt < 12; ++kt) {
        int k0 = kt * 16;
        for (int i4 = tid; i4 < 512; i4 += 256) {
            int r = i4 >> 2, kq = (i4 & 3) * 4;
            int t = m0 + r, k = k0 + kq;
            float4 v;
            if (k < 128) v = *(const float4*)(yn + (size_t)t * 128 + k);
            else         v = *(const float4*)(yl + (size_t)t * 64 + (k - 128));
            sa[r][kq] = v.x; sa[r][kq + 1] = v.y; sa[r][kq + 2] = v.z; sa[r][kq + 3] = v.w;
        }
        {
            int c = tid >> 2, kq = (tid & 3) * 4;
            float4 v = *(const float4*)(mixW + (size_t)(c0 + c) * 192 + k0 + kq);
            sb[c][kq] = v.x; sb[c][kq + 1] = v.y; sb[c][kq + 2] = v.z; sb[c][kq + 3] = v.w;
        }
        __syncthreads();
#pragma unroll
        for (int kk = 0; kk < 16; ++kk) {
            float a[8], bv[4];
#pragma unroll
            for (int i = 0; i < 8; ++i) a[i] = sa[tr + 16 * i][kk];
#pragma unroll
            for (int j = 0; j < 4; ++j) bv[j] = sb[tc + 16 * j][kk];
#pragma unroll
            for (int i = 0; i < 8; ++i)
#pragma unroll
                for (int j = 0; j < 4; ++j) acc[i][j] += a[i] * bv[j];
        }
        __syncthreads();
    }
#pragma unroll
    for (int i = 0; i < 8; ++i) {
        int t = m0 + tr + 16 * i;
        long rg = m_off + t;
        int w = (int)(rg & 15);
        long sq = rg >> 4;
        long b = sq >> 11, n = sq & 2047;
#pragma unroll
        for (int j = 0; j < 4; ++j) {
            int cg = c0 + tc + 16 * j;
            float catv = (cg < 128) ? yn[(size_t)t * 128 + cg]
                                    : yl[(size_t)t * 64 + cg - 128];
            float v = acc[i][j] + mixb[cg];
            float m = silu_f(v) + catv;
            if (cg < 128)
                out_node[((size_t)(b * 16 + w) * 2048 + n) * 128 + cg] = m;
            else
                out_log[((size_t)(b * 16 + w) * 2048 + n) * 64 + (cg - 128)] = m;
        }
    }
}

// ---------------------------------------------------------------------------
extern "C" void kernel_launch(void* const* d_in, const int* in_sizes, int n_in,
                              void* d_out, int out_size, void* d_ws, size_t ws_size,
                              hipStream_t stream) {
    const float* x_node = (const float*)d_in[0];
    const float* x_trace = (const float*)d_in[1];
    const float* x_log = (const float*)d_in[2];
    const float* n_in_w = (const float*)d_in[3];
    const float* n_cw = (const float*)d_in[4];
    const float* n_cb = (const float*)d_in[5];
    const float* n_xp = (const float*)d_in[6];
    const float* n_dtw = (const float*)d_in[7];
    const float* n_dtb = (const float*)d_in[8];
    const float* n_Al = (const float*)d_in[9];
    const float* n_D = (const float*)d_in[10];
    const float* n_ow = (const float*)d_in[11];
    const float* t_in_w = (const float*)d_in[12];
    const float* t_cw = (const float*)d_in[13];
    const float* t_cb = (const float*)d_in[14];
    const float* t_xp = (const float*)d_in[15];
    const float* t_dtw = (const float*)d_in[16];
    const float* t_dtb = (const float*)d_in[17];
    const float* t_Al = (const float*)d_in[18];
    const float* t_D = (const float*)d_in[19];
    const float* t_ow = (const float*)d_in[20];
    const float* l_in_w = (const float*)d_in[21];
    const float* l_cw = (const float*)d_in[22];
    const float* l_cb = (const float*)d_in[23];
    const float* l_xp = (const float*)d_in[24];
    const float* l_dtw = (const float*)d_in[25];
    const float* l_dtb = (const float*)d_in[26];
    const float* l_Al = (const float*)d_in[27];
    const float* l_D = (const float*)d_in[28];
    const float* l_ow = (const float*)d_in[29];
    const float* mix_W = (const float*)d_in[30];
    const float* mix_b = (const float*)d_in[31];
    (void)in_sizes; (void)n_in; (void)out_size;

    float* out = (float*)d_out;
    float* out_trace = out + 16777216;
    float* out_log = out + 33554432;

    // ---- ws layout: [bf16 weight region 589824 B][chunk float region] ----
    unsigned short* wb = (unsigned short*)d_ws;
    unsigned short* nIh = wb;           unsigned short* nIl = wb + 65536;    // 512x128
    unsigned short* nOh = wb + 131072;  unsigned short* nOl = wb + 163840;   // 128x256
    unsigned short* lIh = wb + 196608;  unsigned short* lIl = wb + 212992;   // 256x64
    unsigned short* lOh = wb + 229376;  unsigned short* lOl = wb + 237568;   // 64x128
    unsigned short* tIh = wb + 245760;  unsigned short* tIl = wb + 262144;   // 256x64
    unsigned short* tOh = wb + 278528;  unsigned short* tOl = wb + 286720;   // 64x128
    float* fbase = (float*)d_ws + 147456;
    const unsigned long long avail = (unsigned long long)ws_size - 589824ull;

    // one-time weight splits (graph-captured; re-run each replay, idempotent)
    wsplit<<<256, 256, 0, stream>>>(n_in_w, nIh, nIl, 65536);
    wsplit<<<128, 256, 0, stream>>>(n_ow, nOh, nOl, 32768);
    wsplit<<<64, 256, 0, stream>>>(l_in_w, lIh, lIl, 16384);
    wsplit<<<32, 256, 0, stream>>>(l_ow, lOh, lOl, 8192);
    wsplit<<<64, 256, 0, stream>>>(t_in_w, tIh, tIl, 16384);
    wsplit<<<32, 256, 0, stream>>>(t_ow, tOh, tOl, 8192);

    // ---- node + log + mix, chunked (5376 B/token) ----
    long C = 1;
    while ((unsigned long long)(131072 / C) * 5376ull > avail && C < 16) C <<= 1;
    long Tc = 131072 / C;
    float* xzn = fbase;
    float* gn  = xzn + (size_t)Tc * 512;
    float* yn  = gn  + (size_t)Tc * 256;
    float* xzl = yn  + (size_t)Tc * 128;
    float* gl  = xzl + (size_t)Tc * 256;
    float* yl  = gl  + (size_t)Tc * 128;

    for (long c = 0; c < C; ++c) {
        long m_off = c * Tc;
        gemm_split<128, true, false><<<dim3(Tc / 128, 4), 256, 0, stream>>>(
            x_node, nIh, nIl, xzn, (int)Tc, 512, 128, m_off, 11);
        gemm_split<128, true, false><<<dim3(Tc / 128, 2), 256, 0, stream>>>(
            x_log, lIh, lIl, xzl, (int)Tc, 256, 64, m_off, 11);
        mamba_mid<256, 8><<<Tc / 16, 256, 0, stream>>>(
            xzn, n_cw, n_cb, n_xp, n_dtw, n_dtb, n_Al, n_D, gn);
        mamba_mid<128, 4><<<Tc / 16, 128, 0, stream>>>(
            xzl, l_cw, l_cb, l_xp, l_dtw, l_dtb, l_Al, l_D, gl);
        gemm_split<128, false, false><<<dim3(Tc / 128, 1), 256, 0, stream>>>(
            gn, nOh, nOl, yn, (int)Tc, 128, 256, 0, 0);
        gemm_split<64, false, false><<<dim3(Tc / 128, 1), 256, 0, stream>>>(
            gl, lOh, lOl, yl, (int)Tc, 64, 128, 0, 0);
        mix_kernel<<<dim3(Tc / 128, 3), 256, 0, stream>>>(
            yn, yl, mix_W, mix_b, out, out_log, m_off);
    }

    // ---- trace, chunked (1536 B/token) ----
    long Ct = 1;
    while ((unsigned long long)(262144 / Ct) * 1536ull > avail && Ct < 16) Ct <<= 1;
    long Tt = 262144 / Ct;
    float* xzt = fbase;
    float* gt = xzt + (size_t)Tt * 256;

    for (long c = 0; c < Ct; ++c) {
        long m_off = c * Tt;
        gemm_split<128, true, false><<<dim3(Tt / 128, 2), 256, 0, stream>>>(
            x_trace, tIh, tIl, xzt, (int)Tt, 256, 64, m_off, 12);
        mamba_mid<128, 4><<<Tt / 16, 128, 0, stream>>>(
            xzt, t_cw, t_cb, t_xp, t_dtw, t_dtb, t_Al, t_D, gt);
        gemm_split<64, false, true><<<dim3(Tt / 128, 1), 256, 0, stream>>>(
            gt, tOh, tOl, out_trace, (int)Tt, 64, 128, m_off, 12);
    }
}

// Round 5
// 1425.978 us; speedup vs baseline: 2.1654x; 1.7895x over previous
//
#include <hip/hip_runtime.h>

// B=4, W=16, N=2048, E=4096, Dn=128, De=64, Dl=64, ds=16, d_conv=4, expand=2
// node:  d=128, di=256, dtr=8, T=131072, nr_l2=11, NJ=40
// trace: d=64,  di=128, dtr=4, T=262144, nr_l2=12, NJ=36
// log:   d=64,  di=128, dtr=4, T=131072, nr_l2=11, NJ=36

#define DEV_INLINE __device__ __forceinline__

typedef __attribute__((ext_vector_type(8))) short bf16x8;
typedef __attribute__((ext_vector_type(4))) float f32x4;

DEV_INLINE float silu_f(float v) { return v / (1.0f + __expf(-v)); }

DEV_INLINE unsigned short f2bf(float f) {            // fp32 -> bf16 (RNE)
    unsigned int u = __float_as_uint(f);
    u += 0x7fffu + ((u >> 16) & 1u);
    return (unsigned short)(u >> 16);
}
DEV_INLINE float bf2f(unsigned short b) {
    return __uint_as_float(((unsigned int)b) << 16);
}

// ---------------------------------------------------------------------------
// One-time weight split: w (fp32, n elems) -> bf16 hi + lo arrays.
// ---------------------------------------------------------------------------
__global__ __launch_bounds__(256) void wsplit(
    const float* __restrict__ src, unsigned short* __restrict__ dh,
    unsigned short* __restrict__ dl, int n)
{
    int i = blockIdx.x * 256 + threadIdx.x;
    if (i >= n) return;
    float v = src[i];
    unsigned short h = f2bf(v);
    dh[i] = h;
    dl[i] = f2bf(v - bf2f(h));
}

// ---------------------------------------------------------------------------
// Split-bf16 MFMA GEMM:  C[M][N] = A[M][K](fp32) @ W[N][K]^T (W pre-split).
// acc += Ah*Wh + Ah*Wl + Al*Wh.  BM=128, BK=32, 256 threads (4 waves).
// GATHER: A rows gathered from x (B,16,Nr,D) token order (needs m_off,nr_l2).
// CONV:   epilogue splits cols at DI: xin half gets causal conv(k=4)+SiLU ->
//         u buffer; z half -> Zb buffer. In-wave conv: t = lg*4+q, neighbors
//         from lane-16 via __shfl. (rows local to chunk)
// XMASK:  store only col < Nreal at row pitch Nreal (x_proj dbc output).
// TRN:    scatter C to (B,16,Nr,N) final layout (trace out_proj).
// ---------------------------------------------------------------------------
template<int BN, bool GATHER, bool CONV, bool TRN, bool XMASK>
__global__ __launch_bounds__(256) void gemm_split(
    const float* __restrict__ A,
    const unsigned short* __restrict__ Wh,
    const unsigned short* __restrict__ Wl,
    float* __restrict__ C,              // u buffer when CONV
    float* __restrict__ Zb,             // z buffer when CONV
    const float* __restrict__ conv_w, const float* __restrict__ conv_b,
    int N, int K, int DI, int Nreal, long m_off, int nr_l2)
{
    constexpr int BM = 128, BK = 32;
    __shared__ unsigned short sAh[BM][40], sAl[BM][40];   // 80 B pitch
    __shared__ unsigned short sBh[BN][40], sBl[BN][40];

    const int tid = threadIdx.x;
    const int m0 = blockIdx.x * BM;
    const int n0 = blockIdx.y * BN;
    const int lane = tid & 63, wv = tid >> 6;
    const int lr = lane & 15, lg = lane >> 4;
    constexpr int MT = (BN == 128) ? 4 : 2;
    const int wm = (BN == 128) ? (wv >> 1) * 64 : wv * 32;
    const int wn = (BN == 128) ? (wv & 1) * 64 : 0;

    f32x4 acc[MT][4] = {};

    for (int kt = 0; kt < K / BK; ++kt) {
        const int k0 = kt * BK;
#pragma unroll
        for (int p = 0; p < BM * BK / 1024; ++p) {
            int i4 = tid + p * 256;
            int r = i4 >> 3, c4 = (i4 & 7) * 4;
            const float* src;
            if (GATHER) {
                long rg = m_off + m0 + r;
                long sq = rg >> 4; int w = (int)(rg & 15);
                long b = sq >> nr_l2, n = sq & ((1L << nr_l2) - 1);
                src = A + ((((b << 4) + w) << nr_l2) + n) * (long)K + k0 + c4;
            } else {
                src = A + (size_t)(m0 + r) * K + k0 + c4;
            }
            float4 v = *(const float4*)src;
            ushort4 hi, lo;
            hi.x = f2bf(v.x); lo.x = f2bf(v.x - bf2f(hi.x));
            hi.y = f2bf(v.y); lo.y = f2bf(v.y - bf2f(hi.y));
            hi.z = f2bf(v.z); lo.z = f2bf(v.z - bf2f(hi.z));
            hi.w = f2bf(v.w); lo.w = f2bf(v.w - bf2f(hi.w));
            *(ushort4*)&sAh[r][c4] = hi;
            *(ushort4*)&sAl[r][c4] = lo;
        }
#pragma unroll
        for (int p = 0; p < BN * BK / 2048; ++p) {
            int i8 = tid + p * 256;
            int r = i8 >> 2, c8 = (i8 & 3) * 8;
            *(bf16x8*)&sBh[r][c8] = *(const bf16x8*)(Wh + (size_t)(n0 + r) * K + k0 + c8);
            *(bf16x8*)&sBl[r][c8] = *(const bf16x8*)(Wl + (size_t)(n0 + r) * K + k0 + c8);
        }
        __syncthreads();

        bf16x8 aH[MT], aL[MT];
#pragma unroll
        for (int mt = 0; mt < MT; ++mt) {
            aH[mt] = *(const bf16x8*)&sAh[wm + mt * 16 + lr][lg * 8];
            aL[mt] = *(const bf16x8*)&sAl[wm + mt * 16 + lr][lg * 8];
        }
#pragma unroll
        for (int nt = 0; nt < 4; ++nt) {
            bf16x8 bH = *(const bf16x8*)&sBh[wn + nt * 16 + lr][lg * 8];
            bf16x8 bL = *(const bf16x8*)&sBl[wn + nt * 16 + lr][lg * 8];
#pragma unroll
            for (int mt = 0; mt < MT; ++mt) {
                acc[mt][nt] = __builtin_amdgcn_mfma_f32_16x16x32_bf16(aH[mt], bH, acc[mt][nt], 0, 0, 0);
                acc[mt][nt] = __builtin_amdgcn_mfma_f32_16x16x32_bf16(aH[mt], bL, acc[mt][nt], 0, 0, 0);
                acc[mt][nt] = __builtin_amdgcn_mfma_f32_16x16x32_bf16(aL[mt], bH, acc[mt][nt], 0, 0, 0);
            }
        }
        __syncthreads();
    }

    // ---- epilogue (D layout: col=lane&15, row=(lane>>4)*4+reg) ----
    if (CONV) {
        const bool is_x = (n0 < DI);     // block-uniform
        if (is_x) {
            // conv in registers: within one (mt,nt), lanes hold a 16(t)x16(ch)
            // tile of ONE sequence: t = lg*4+q. Causal neighbors from lane-16.
            const int src = (lg == 0) ? lane : (lane - 16);
#pragma unroll
            for (int mt = 0; mt < MT; ++mt) {
#pragma unroll
                for (int nt = 0; nt < 4; ++nt) {
                    int ch = n0 + wn + nt * 16 + lr;
                    float4 cw = *(const float4*)(conv_w + ch * 4);
                    float cb = conv_b[ch];
                    float v0 = acc[mt][nt][0], v1 = acc[mt][nt][1];
                    float v2 = acc[mt][nt][2], v3 = acc[mt][nt][3];
                    float p1 = __shfl(v1, src, 64);
                    float p2 = __shfl(v2, src, 64);
                    float p3 = __shfl(v3, src, 64);
                    if (lg == 0) { p1 = 0.f; p2 = 0.f; p3 = 0.f; }
                    float x3[4] = { p1, p2, p3, v0 };   // x[t-3]
                    float x2[4] = { p2, p3, v0, v1 };   // x[t-2]
                    float x1[4] = { p3, v0, v1, v2 };   // x[t-1]
                    float xt[4] = { v0, v1, v2, v3 };   // x[t]
#pragma unroll
                    for (int q = 0; q < 4; ++q) {
                        float xc = cb + cw.x * x3[q] + cw.y * x2[q]
                                      + cw.z * x1[q] + cw.w * xt[q];
                        int row = m0 + wm + mt * 16 + lg * 4 + q;  // local
                        C[(size_t)row * DI + ch] = silu_f(xc);
                    }
                }
            }
        } else {
#pragma unroll
            for (int mt = 0; mt < MT; ++mt) {
#pragma unroll
                for (int nt = 0; nt < 4; ++nt) {
                    int ch = n0 + wn + nt * 16 + lr - DI;
#pragma unroll
                    for (int q = 0; q < 4; ++q) {
                        int row = m0 + wm + mt * 16 + lg * 4 + q;
                        Zb[(size_t)row * DI + ch] = acc[mt][nt][q];
                    }
                }
            }
        }
        return;
    }

#pragma unroll
    for (int mt = 0; mt < MT; ++mt) {
        int row0 = m0 + wm + mt * 16 + lg * 4;
#pragma unroll
        for (int nt = 0; nt < 4; ++nt) {
            int col = n0 + wn + nt * 16 + lr;
#pragma unroll
            for (int q = 0; q < 4; ++q) {
                int row = row0 + q;
                if (XMASK) {
                    if (col < Nreal)
                        C[(size_t)row * Nreal + col] = acc[mt][nt][q];
                } else if (TRN) {
                    long rg = m_off + row;
                    long sq = rg >> 4; int w = (int)(rg & 15);
                    long b = sq >> nr_l2, e = sq & ((1L << nr_l2) - 1);
                    C[((((b << 4) + w) << nr_l2) + e) * (long)N + col] = acc[mt][nt][q];
                } else {
                    C[(size_t)row * N + col] = acc[mt][nt][q];
                }
            }
        }
    }
}

// ---------------------------------------------------------------------------
// Scan kernel: dt_proj + softplus + selective scan + D-skip + z-gate.
// One block = one sequence (16 tokens), thread == channel. Inputs u (conv'd),
// z, dbc (pitch NJ). Fast path: A_log row = log(1..16) -> dA = r^(s+1).
// ---------------------------------------------------------------------------
template<int DI, int DTR>
__global__ __launch_bounds__(DI) void scan_kernel(
    const float* __restrict__ u,        // (Tc, DI)
    const float* __restrict__ zb,       // (Tc, DI)
    const float* __restrict__ dbc,      // (Tc, NJ)
    const float* __restrict__ dt_w,     // (DI, DTR)
    const float* __restrict__ dt_b,     // (DI)
    const float* __restrict__ A_log,    // (DI, 16)
    const float* __restrict__ Dp,       // (DI)
    float* __restrict__ g)              // (Tc, DI)
{
    constexpr int NJ = DTR + 32;
    __shared__ float sdbc[16][NJ];

    const int ch = threadIdx.x;
    const long s = blockIdx.x;

    for (int p = ch; p < 16 * NJ; p += DI) {
        int r = p / NJ, c = p % NJ;
        sdbc[r][c] = dbc[((size_t)s * 16 + r) * NJ + c];
    }
    float uu[16], zz[16];
#pragma unroll
    for (int t = 0; t < 16; ++t) {
        uu[t] = u[((size_t)s * 16 + t) * DI + ch];
        zz[t] = zb[((size_t)s * 16 + t) * DI + ch];
    }
    __syncthreads();

    float dtw[DTR];
#pragma unroll
    for (int r = 0; r < DTR; ++r) dtw[r] = dt_w[ch * DTR + r];
    float dtb = dt_b[ch];
    float Dch = Dp[ch];
    float a_s[16];
    bool geo = true;
#pragma unroll
    for (int ss = 0; ss < 16; ++ss) {
        a_s[ss] = -__expf(A_log[ch * 16 + ss]);
        geo = geo && (__builtin_fabsf(a_s[ss] + (float)(ss + 1)) < 1e-3f);
    }
    float h[16];
#pragma unroll
    for (int ss = 0; ss < 16; ++ss) h[ss] = 0.f;

    float* gout = g + (size_t)s * 16 * DI + ch;
    for (int t = 0; t < 16; ++t) {
        float dtv = dtb;
#pragma unroll
        for (int r = 0; r < DTR; ++r) dtv += sdbc[t][r] * dtw[r];
        dtv = (dtv > 20.f) ? dtv : __logf(1.f + __expf(dtv));   // softplus
        float du = dtv * uu[t];
        float yt = 0.f;
        if (geo) {
            float r1 = __expf(-dtv);
            float pw = 1.f;
#pragma unroll
            for (int ss = 0; ss < 16; ++ss) {
                pw *= r1;                         // pw = exp(dt*a_s[ss])
                h[ss] = pw * h[ss] + du * sdbc[t][DTR + ss];
                yt += h[ss] * sdbc[t][DTR + 16 + ss];
            }
        } else {
#pragma unroll
            for (int ss = 0; ss < 16; ++ss) {
                float dA = __expf(dtv * a_s[ss]);
                h[ss] = dA * h[ss] + du * sdbc[t][DTR + ss];
                yt += h[ss] * sdbc[t][DTR + 16 + ss];
            }
        }
        yt += uu[t] * Dch;
        gout[(size_t)t * DI] = yt * silu_f(zz[t]);
    }
}

// ---------------------------------------------------------------------------
// Mix: cat = [yn_c | yl_c] (Tc x 192); mixed = silu(cat @ W^T + b) + cat;
// transposed split-write to out_node / out_log.
// ---------------------------------------------------------------------------
__global__ __launch_bounds__(256) void mix_kernel(
    const float* __restrict__ yn, const float* __restrict__ yl,
    const float* __restrict__ mixW, const float* __restrict__ mixb,
    float* __restrict__ out_node, float* __restrict__ out_log, long m_off)
{
    __shared__ float sa[128][17];
    __shared__ float sb[64][17];
    const int tid = threadIdx.x;
    const int m0 = blockIdx.x * 128;
    const int c0 = blockIdx.y * 64;
    const int tr = tid & 15, tc = tid >> 4;
    float acc[8][4] = {};
    for (int kt = 0; kt < 12; ++kt) {
        int k0 = kt * 16;
        for (int i4 = tid; i4 < 512; i4 += 256) {
            int r = i4 >> 2, kq = (i4 & 3) * 4;
            int t = m0 + r, k = k0 + kq;
            float4 v;
            if (k < 128) v = *(const float4*)(yn + (size_t)t * 128 + k);
            else         v = *(const float4*)(yl + (size_t)t * 64 + (k - 128));
            sa[r][kq] = v.x; sa[r][kq + 1] = v.y; sa[r][kq + 2] = v.z; sa[r][kq + 3] = v.w;
        }
        {
            int c = tid >> 2, kq = (tid & 3) * 4;
            float4 v = *(const float4*)(mixW + (size_t)(c0 + c) * 192 + k0 + kq);
            sb[c][kq] = v.x; sb[c][kq + 1] = v.y; sb[c][kq + 2] = v.z; sb[c][kq + 3] = v.w;
        }
        __syncthreads();
#pragma unroll
        for (int kk = 0; kk < 16; ++kk) {
            float a[8], bv[4];
#pragma unroll
            for (int i = 0; i < 8; ++i) a[i] = sa[tr + 16 * i][kk];
#pragma unroll
            for (int j = 0; j < 4; ++j) bv[j] = sb[tc + 16 * j][kk];
#pragma unroll
            for (int i = 0; i < 8; ++i)
#pragma unroll
                for (int j = 0; j < 4; ++j) acc[i][j] += a[i] * bv[j];
        }
        __syncthreads();
    }
#pragma unroll
    for (int i = 0; i < 8; ++i) {
        int t = m0 + tr + 16 * i;
        long rg = m_off + t;
        int w = (int)(rg & 15);
        long sq = rg >> 4;
        long b = sq >> 11, n = sq & 2047;
#pragma unroll
        for (int j = 0; j < 4; ++j) {
            int cg = c0 + tc + 16 * j;
            float catv = (cg < 128) ? yn[(size_t)t * 128 + cg]
                                    : yl[(size_t)t * 64 + cg - 128];
            float v = acc[i][j] + mixb[cg];
            float m = silu_f(v) + catv;
            if (cg < 128)
                out_node[((size_t)(b * 16 + w) * 2048 + n) * 128 + cg] = m;
            else
                out_log[((size_t)(b * 16 + w) * 2048 + n) * 64 + (cg - 128)] = m;
        }
    }
}

// ---------------------------------------------------------------------------
extern "C" void kernel_launch(void* const* d_in, const int* in_sizes, int n_in,
                              void* d_out, int out_size, void* d_ws, size_t ws_size,
                              hipStream_t stream) {
    const float* x_node = (const float*)d_in[0];
    const float* x_trace = (const float*)d_in[1];
    const float* x_log = (const float*)d_in[2];
    const float* n_in_w = (const float*)d_in[3];
    const float* n_cw = (const float*)d_in[4];
    const float* n_cb = (const float*)d_in[5];
    const float* n_xp = (const float*)d_in[6];
    const float* n_dtw = (const float*)d_in[7];
    const float* n_dtb = (const float*)d_in[8];
    const float* n_Al = (const float*)d_in[9];
    const float* n_D = (const float*)d_in[10];
    const float* n_ow = (const float*)d_in[11];
    const float* t_in_w = (const float*)d_in[12];
    const float* t_cw = (const float*)d_in[13];
    const float* t_cb = (const float*)d_in[14];
    const float* t_xp = (const float*)d_in[15];
    const float* t_dtw = (const float*)d_in[16];
    const float* t_dtb = (const float*)d_in[17];
    const float* t_Al = (const float*)d_in[18];
    const float* t_D = (const float*)d_in[19];
    const float* t_ow = (const float*)d_in[20];
    const float* l_in_w = (const float*)d_in[21];
    const float* l_cw = (const float*)d_in[22];
    const float* l_cb = (const float*)d_in[23];
    const float* l_xp = (const float*)d_in[24];
    const float* l_dtw = (const float*)d_in[25];
    const float* l_dtb = (const float*)d_in[26];
    const float* l_Al = (const float*)d_in[27];
    const float* l_D = (const float*)d_in[28];
    const float* l_ow = (const float*)d_in[29];
    const float* mix_W = (const float*)d_in[30];
    const float* mix_b = (const float*)d_in[31];
    (void)in_sizes; (void)n_in; (void)out_size;

    float* out = (float*)d_out;
    float* out_trace = out + 16777216;
    float* out_log = out + 33554432;

    // ---- ws: bf16 weight region (shorts), then chunk float region ----
    unsigned short* wb = (unsigned short*)d_ws;
    size_t o = 0;
    unsigned short* nIh = wb + o; o += 65536; unsigned short* nIl = wb + o; o += 65536;  // 512x128
    unsigned short* nOh = wb + o; o += 32768; unsigned short* nOl = wb + o; o += 32768;  // 128x256
    unsigned short* lIh = wb + o; o += 16384; unsigned short* lIl = wb + o; o += 16384;  // 256x64
    unsigned short* lOh = wb + o; o += 8192;  unsigned short* lOl = wb + o; o += 8192;   // 64x128
    unsigned short* tIh = wb + o; o += 16384; unsigned short* tIl = wb + o; o += 16384;  // 256x64
    unsigned short* tOh = wb + o; o += 8192;  unsigned short* tOl = wb + o; o += 8192;   // 64x128
    unsigned short* nXh = wb + o; o += 16384; unsigned short* nXl = wb + o; o += 16384;  // 64x256 (40 used)
    unsigned short* lXh = wb + o; o += 8192;  unsigned short* lXl = wb + o; o += 8192;   // 64x128 (36 used)
    unsigned short* tXh = wb + o; o += 8192;  unsigned short* tXl = wb + o; o += 8192;   // 64x128 (36 used)
    float* fbase = (float*)d_ws + (o / 2);                  // o even
    const unsigned long long avail = (unsigned long long)ws_size - o * 2ull;

    // one-time weight splits (idempotent; re-run every launch — ws is poisoned)
    wsplit<<<256, 256, 0, stream>>>(n_in_w, nIh, nIl, 65536);
    wsplit<<<128, 256, 0, stream>>>(n_ow, nOh, nOl, 32768);
    wsplit<<<64, 256, 0, stream>>>(l_in_w, lIh, lIl, 16384);
    wsplit<<<32, 256, 0, stream>>>(l_ow, lOh, lOl, 8192);
    wsplit<<<64, 256, 0, stream>>>(t_in_w, tIh, tIl, 16384);
    wsplit<<<32, 256, 0, stream>>>(t_ow, tOh, tOl, 8192);
    wsplit<<<40, 256, 0, stream>>>(n_xp, nXh, nXl, 10240);   // 40x256
    wsplit<<<18, 256, 0, stream>>>(l_xp, lXh, lXl, 4608);    // 36x128
    wsplit<<<18, 256, 0, stream>>>(t_xp, tXh, tXl, 4608);    // 36x128

    // ---- node + log + mix, chunked (5680 B/token) ----
    long C = 1;
    while ((unsigned long long)(131072 / C) * 5680ull > avail && C < 16) C <<= 1;
    long Tc = 131072 / C;
    float* p = fbase;
    float* un = p; p += Tc * 256;
    float* zn = p; p += Tc * 256;
    float* dn = p; p += Tc * 40;
    float* gn = p; p += Tc * 256;
    float* yn = p; p += Tc * 128;
    float* ul = p; p += Tc * 128;
    float* zl = p; p += Tc * 128;
    float* dl = p; p += Tc * 36;
    float* gl = p; p += Tc * 128;
    float* yl = p; p += Tc * 64;

    for (long c = 0; c < C; ++c) {
        long m_off = c * Tc;
        // in_proj + conv + silu -> u, z
        gemm_split<128, true, true, false, false><<<dim3(Tc / 128, 4), 256, 0, stream>>>(
            x_node, nIh, nIl, un, zn, n_cw, n_cb, 512, 128, 256, 0, m_off, 11);
        gemm_split<128, true, true, false, false><<<dim3(Tc / 128, 2), 256, 0, stream>>>(
            x_log, lIh, lIl, ul, zl, l_cw, l_cb, 256, 64, 128, 0, m_off, 11);
        // x_proj -> dbc (pitch NJ)
        gemm_split<64, false, false, false, true><<<dim3(Tc / 128, 1), 256, 0, stream>>>(
            un, nXh, nXl, dn, nullptr, nullptr, nullptr, 64, 256, 0, 40, 0, 0);
        gemm_split<64, false, false, false, true><<<dim3(Tc / 128, 1), 256, 0, stream>>>(
            ul, lXh, lXl, dl, nullptr, nullptr, nullptr, 64, 128, 0, 36, 0, 0);
        // scan -> g
        scan_kernel<256, 8><<<Tc / 16, 256, 0, stream>>>(
            un, zn, dn, n_dtw, n_dtb, n_Al, n_D, gn);
        scan_kernel<128, 4><<<Tc / 16, 128, 0, stream>>>(
            ul, zl, dl, l_dtw, l_dtb, l_Al, l_D, gl);
        // out_proj -> y
        gemm_split<128, false, false, false, false><<<dim3(Tc / 128, 1), 256, 0, stream>>>(
            gn, nOh, nOl, yn, nullptr, nullptr, nullptr, 128, 256, 0, 0, 0, 0);
        gemm_split<64, false, false, false, false><<<dim3(Tc / 128, 1), 256, 0, stream>>>(
            gl, lOh, lOl, yl, nullptr, nullptr, nullptr, 64, 128, 0, 0, 0, 0);
        // mix + final transposed writes
        mix_kernel<<<dim3(Tc / 128, 3), 256, 0, stream>>>(
            yn, yl, mix_W, mix_b, out, out_log, m_off);
    }

    // ---- trace, chunked (1680 B/token) ----
    long Ct = 1;
    while ((unsigned long long)(262144 / Ct) * 1680ull > avail && Ct < 16) Ct <<= 1;
    long Tt = 262144 / Ct;
    float* q = fbase;
    float* ut = q; q += Tt * 128;
    float* zt = q; q += Tt * 128;
    float* dt = q; q += Tt * 36;
    float* gt = q; q += Tt * 128;

    for (long c = 0; c < Ct; ++c) {
        long m_off = c * Tt;
        gemm_split<128, true, true, false, false><<<dim3(Tt / 128, 2), 256, 0, stream>>>(
            x_trace, tIh, tIl, ut, zt, t_cw, t_cb, 256, 64, 128, 0, m_off, 12);
        gemm_split<64, false, false, false, true><<<dim3(Tt / 128, 1), 256, 0, stream>>>(
            ut, tXh, tXl, dt, nullptr, nullptr, nullptr, 64, 128, 0, 36, 0, 0);
        scan_kernel<128, 4><<<Tt / 16, 128, 0, stream>>>(
            ut, zt, dt, t_dtw, t_dtb, t_Al, t_D, gt);
        gemm_split<64, false, false, true, false><<<dim3(Tt / 128, 1), 256, 0, stream>>>(
            gt, tOh, tOl, out_trace, nullptr, nullptr, nullptr, 64, 128, 0, 0, m_off, 12);
    }
}